// Round 8
// baseline (6538.181 us; speedup 1.0000x reference)
//
#include <hip/hip_runtime.h>
#include <math.h>

// ============================================================================
// S2CNN regression — round 7.
//  R6 profile: k_analysis dominates HBM traffic (FETCH 443MB/dispatch at
//  15 GB/s): k-loop strides 32KB through X, 11x re-read across degrees.
//  This round: k_ana2 — one block per (signal, freq-row m); X row staged in
//  LDS per k (coalesced, read once); <=4 outputs/thread in registers; wig
//  table read at coalesced addresses (L2/L3-resident). Analysis rows/cols
//  outside the output bandwidth are never read. Everything else unchanged.
// ============================================================================

#define PI_D 3.14159265358979323846

__host__ __device__ __forceinline__ int offl_(int l) { return l*(2*l-1)*(2*l+1)/3; }
static inline int Sof(int b) { return b*(4*b*b-1)/3; }           // sum_{l<b}(2l+1)^2
static inline unsigned cdiv(long a, long b) { return (unsigned)((a + b - 1) / b); }

__device__ __constant__ float COS6[6] = {1.f, .5f, -.5f, -1.f, -.5f, .5f};
__device__ __constant__ float SIN6[6] = {0.f, 0.8660254037844386f, 0.8660254037844386f,
                                         0.f, -0.8660254037844386f, -0.8660254037844386f};

// ---------------- table generation ----------------
__global__ void k_lf(double* lf) {
  int n = threadIdx.x;
  double s = 0.0;
  for (int j = 2; j <= n; ++j) s += log((double)j);
  lf[n] = s;
}

__global__ void k_qw(int b, float* out) {
  int k = threadIdx.x, K = 2*b;
  if (k >= K) return;
  double beta = PI_D*(2*k+1)/(4.0*b);
  double s = 0.0;
  for (int j = 0; j < b; ++j)
    s += sin(PI_D*(double)(2*k+1)*(double)(2*j+1)/(4.0*b)) / (double)(2*j+1);
  out[k] = (float)((2.0/b)*sin(beta)*s);
}

// d^l_{m,n}(beta), explicit Jacobi sum, fp64.
__global__ void k_wigner(int L, int K, double beta0, const double* __restrict__ lf,
                         float* __restrict__ out) {
  int l = blockIdx.y;
  int d = 2*l+1, dd = d*d;
  long total = (long)K*dd;
  long idx = (long)blockIdx.x*blockDim.x + threadIdx.x;
  if (idx >= total) return;
  int k = (int)(idx / dd), r = (int)(idx % dd);
  int mi = r/d, ni = r - mi*d, m = mi-l, n = ni-l;
  double beta = (K == 1) ? beta0 : PI_D*(double)(2*k+1)/(2.0*K);
  double cb = cos(0.5*beta), sb = sin(0.5*beta);
  double lc = log(cb), ls = log(sb);
  double pref = 0.5*(lf[l+m]+lf[l-m]+lf[l+n]+lf[l-n]);
  int smin = (n-m > 0) ? (n-m) : 0;
  int smax = (l+n < l-m) ? (l+n) : (l-m);
  double sum = 0.0;
  for (int s = smin; s <= smax; ++s) {
    double t = pref - lf[l+n-s] - lf[s] - lf[m-n+s] - lf[l-m-s]
             + (double)(2*l+n-m-2*s)*lc + (double)(m-n+2*s)*ls;
    double e = exp(t);
    sum += ((m-n+s) & 1) ? -e : e;
  }
  out[(long)K*offl_(l) + idx] = (float)sum;
}

// ---------------- s2 front: 1-D forward DFT (centered output) ----------------
__global__ void k_dft1(const float* __restrict__ in, float2* __restrict__ out, int K) {
  __shared__ float row[64];
  int tid = threadIdx.x;
  long base = (long)blockIdx.x * K;
  row[tid] = in[base + tid];
  __syncthreads();
  int i = tid;
  float2 acc = make_float2(0.f, 0.f);
  float c0 = 6.28318530717958647692f / K;
  for (int j = 0; j < K; ++j) {
    int r = (j * ((K + K/2 - i) & (K-1))) & (K-1);
    float s, c; sincosf(c0 * (float)r, &s, &c);
    acc.x += row[j]*c; acc.y += row[j]*s;
  }
  out[base + i] = acc;
}

// ---------------- fused transition kernel ----------------
__device__ __forceinline__ void fft_axis(float2* T, int P, float2* S, const float2* TW,
                                         int K, int axis, float fsign,
                                         int tid, int bs) {
  const int half = K >> 1;
  int stages = 0; for (int t = K; t > 1; t >>= 1) ++stages;
  for (int b0 = 0; b0 < K; b0 += half) {
    int cur = 0;
    int l = half, m = 1;
    for (int s = 0; s < stages; ++s) {
      for (int t = tid; t < half*half; t += bs) {
        int line = t / half, b = t - (t/half)*half;
        int j = b / m, k = b - (b/m)*m;
        int i0 = k + j*m, i1 = i0 + l*m;
        int o0 = k + 2*j*m, o1 = o0 + m;
        float2 a, bb;
        if (cur == 0) {
          int t0i = axis ? (i0*P + b0 + line) : ((b0+line)*P + i0);
          int t1i = axis ? (i1*P + b0 + line) : ((b0+line)*P + i1);
          a = T[t0i]; bb = T[t1i];
        } else {
          a = S[line*K + i0]; bb = S[line*K + i1];
        }
        float2 w = TW[j*m]; w.y *= fsign;
        float2 dv = make_float2(a.x - bb.x, a.y - bb.y);
        float2 t1 = make_float2(dv.x*w.x - dv.y*w.y, dv.x*w.y + dv.y*w.x);
        float2 t0 = make_float2(a.x + bb.x, a.y + bb.y);
        if (cur == 0) {
          S[line*K + o0] = t0; S[line*K + o1] = t1;
        } else {
          int d0i = axis ? (o0*P + b0 + line) : ((b0+line)*P + o0);
          int d1i = axis ? (o1*P + b0 + line) : ((b0+line)*P + o1);
          T[d0i] = t0; T[d1i] = t1;
        }
      }
      __syncthreads();
      cur ^= 1; l >>= 1; m <<= 1;
    }
    if (cur == 1) {
      for (int t = tid; t < half*K; t += bs) {
        int line = t / K, e = t - (t/K)*K;
        int ti = axis ? (e*P + b0 + line) : ((b0+line)*P + e);
        T[ti] = S[line*K + e];
      }
      __syncthreads();
    }
  }
}

__global__ void k_trans(const float2* __restrict__ yl, int ylS,
                        const float* __restrict__ wig, int Lsyn,
                        float2* __restrict__ outX, float* __restrict__ outR,
                        int K, int fwd) {
  extern __shared__ float2 smc[];
  const int P = K + 1;
  float2* TW = smc;
  float2* T  = smc + K/2;
  float2* S  = T + K*P;
  const int tid = threadIdx.x, bs = blockDim.x;
  const int ci = blockIdx.x / K, k = blockIdx.x - ci*K;
  const int KK = K*K, Kh = K/2;
  const float c0 = 6.28318530717958647692f / K;
  for (int t = tid; t < Kh; t += bs) {
    float s, c; sincosf(c0 * (float)t, &s, &c);
    TW[t] = make_float2(c, -s);
  }
  for (int idx = tid; idx < KK; idx += bs) {
    int fm = idx / K, fn = idx - (idx/K)*K;
    int m = (fm ^ Kh) - Kh, n = (fn ^ Kh) - Kh;
    int am = m < 0 ? -m : m, an = n < 0 ? -n : n;
    int lmin = am > an ? am : an;
    float2 acc = make_float2(0.f, 0.f);
    for (int l = lmin; l < Lsyn; ++l) {
      int d = 2*l+1;
      int r = (m+l)*d + (n+l);
      float wv = wig[(size_t)K*offl_(l) + (size_t)k*d*d + r];
      float2 yv = yl[(size_t)ci*ylS + offl_(l) + r];
      acc.x += wv*yv.x; acc.y += wv*yv.y;
    }
    T[fm*P + fn] = acc;
  }
  __syncthreads();
  fft_axis(T, P, S, TW, K, 0, -1.f, tid, bs);
  fft_axis(T, P, S, TW, K, 1, -1.f, tid, bs);
  for (int idx = tid; idx < KK; idx += bs) {
    int fm = idx / K, fn = idx - (idx/K)*K;
    T[fm*P + fn] = make_float2(fmaxf(T[fm*P + fn].x, 0.f), 0.f);
  }
  __syncthreads();
  if (fwd) {
    fft_axis(T, P, S, TW, K, 0, 1.f, tid, bs);
    fft_axis(T, P, S, TW, K, 1, 1.f, tid, bs);
    float2* o = outX + ((size_t)ci*K + k)*KK;
    for (int idx = tid; idx < KK; idx += bs)
      o[idx] = T[(idx/K)*P + (idx - (idx/K)*K)];
  } else {
    float* o = outR + ((size_t)ci*K + k)*KK;
    for (int idx = tid; idx < KK; idx += bs)
      o[idx] = T[(idx/K)*P + (idx - (idx/K)*K)].x;
  }
}

// ---------------- row-streaming Wigner analysis ----------------
// One block per (chunk-signal, freq-row m). X row staged in LDS per k
// (coalesced, each row read exactly once); <=4 outputs (l,ni) per thread in
// registers; wig reads coalesced from the L2/L3-resident table.
// Writes xh in GEMM-native layout: xh[BCall*offl(l) + (b*d+mi)*C*d + c*d + ni]
__global__ __launch_bounds__(256)
void k_ana2(const float2* __restrict__ X, const float* __restrict__ wig,
            const float* __restrict__ qw, float2* __restrict__ xh,
            int K, int Lana, int s0, int C, int BCall) {
  const int nrows = 2*Lana - 1;
  const int bcl = blockIdx.x / nrows;
  const int rowi = blockIdx.x - bcl*nrows;
  const int m = rowi - (Lana - 1);
  const int am = m < 0 ? -m : m;
  const int fm = (m + K) & (K - 1);
  const int bc = s0 + bcl;
  const int b = bc / C, c = bc - b*C;
  const int nout = Lana*Lana - am*am;     // sum_{l=am}^{Lana-1}(2l+1)
  const int tid = threadIdx.x;

  __shared__ float2 row[64];
  __shared__ float qs[64];

  float2 acc[4] = {{0,0},{0,0},{0,0},{0,0}};
  int obase[4], odd[4], ofn[4];
  size_t oaddr[4];
  int ocnt = 0;
  for (int oi = tid; oi < nout && ocnt < 4; oi += 256) {
    int rem = oi, l = am;
    while (rem >= 2*l+1) { rem -= 2*l+1; ++l; }
    int ni = rem, d = 2*l+1;
    int mi = m + l;
    obase[ocnt] = K*offl_(l) + mi*d + ni;
    odd[ocnt]   = d*d;
    int n = ni - l;
    ofn[ocnt]   = (n + K) & (K-1);
    oaddr[ocnt] = (size_t)BCall*offl_(l) + ((size_t)(b*d + mi)*C + c)*d + ni;
    ++ocnt;
  }

  for (int t = tid; t < K; t += 256) qs[t] = qw[t];

  const float2* Xrow = X + (size_t)bcl*K*K*K + (size_t)fm*K;
  for (int k = 0; k < K; ++k) {
    __syncthreads();
    for (int t = tid; t < K; t += 256) row[t] = Xrow[(size_t)k*K*K + t];
    __syncthreads();
    float q = qs[k];
    #pragma unroll 4
    for (int u = 0; u < ocnt; ++u) {
      float wv = wig[obase[u] + k*odd[u]] * q;
      float2 xv = row[ofn[u]];
      acc[u].x += wv*xv.x;
      acc[u].y += wv*xv.y;
    }
  }
  for (int u = 0; u < ocnt; ++u) xh[oaddr[u]] = acc[u];
}

// s2 variant: XS2 CENTERED (from k_dft1). stride 1024, offset l^2.
__global__ void k_analysis_s2(const float2* __restrict__ X, const float* __restrict__ wig,
                              const float* __restrict__ qw, float2* __restrict__ xh,
                              int BC, int K) {
  int l = blockIdx.y, d = 2*l+1, dd = d*d;
  long total = (long)BC*d;
  long idx = (long)blockIdx.x*blockDim.x + threadIdx.x;
  if (idx >= total) return;
  int bc = (int)(idx / d), mi = (int)(idx % d), m = mi - l;
  const float* wl = wig + (long)K*offl_(l);
  float2 acc = make_float2(0.f, 0.f);
  for (int k = 0; k < K; ++k) {
    float w = qw[k] * wl[(long)k*dd + mi*d + l];
    float2 xv = X[((long)bc*K + k)*K + (K/2+m)];
    acc.x += w*xv.x; acc.y += w*xv.y;
  }
  xh[(long)bc*1024 + l*l + mi] = acc;
}

// ---------------- 6x6 phase table of the SO(3) conv weights ----------------
__global__ void k_wf(const float* __restrict__ w, float2* __restrict__ wf, int CF) {
  long idx = (long)blockIdx.x*blockDim.x + threadIdx.x;
  if (idx >= (long)CF*36) return;
  int cf = (int)(idx / 36), r = (int)(idx % 36);
  int mm = r / 6, nn = r - (r/6)*6;
  const float* wp = w + (long)cf*36;
  float re = 0.f, im = 0.f;
  for (int a = 0; a < 6; ++a) {
    int pa = (mm*a) % 6;
    for (int g = 0; g < 6; ++g) {
      int p = (pa + nn*g) % 6;
      float wv = wp[a*6 + g];
      re += wv*COS6[p]; im += wv*SIN6[p];
    }
  }
  wf[idx] = make_float2(re, im);
}

__global__ void k_kh_s2(const float* __restrict__ w, const float* __restrict__ d0,
                        float2* __restrict__ kh, int C, int F) {
  int l = blockIdx.y, d = 2*l+1;
  long total = (long)C*F*d;
  long idx = (long)blockIdx.x*blockDim.x + threadIdx.x;
  if (idx >= total) return;
  int cf = (int)(idx / d), mi = (int)(idx % d), m = mi - l;
  const float* wp = w + (long)cf*6;
  float re = 0.f, im = 0.f;
  for (int j = 0; j < 6; ++j) {
    int p = ((-m*j) % 6 + 6) % 6;
    re += wp[j]*COS6[p]; im += wp[j]*SIN6[p];
  }
  float dv = d0[offl_(l) + mi*d + l];
  kh[(long)cf*1024 + l*l + mi] = make_float2(re*dv, im*dv);
}

// s2 rank-1: yl[b,f,m,n] = sum_c xh[b,c,m]*kh[c,f,n]
__global__ void k_rank1(const float2* __restrict__ xh, const float2* __restrict__ kh,
                        float2* __restrict__ yl, int B, int C, int F, int Sout) {
  int l = blockIdx.y, d = 2*l+1, dd = d*d;
  long total = (long)B*F*dd;
  long idx = (long)blockIdx.x*blockDim.x + threadIdx.x;
  if (idx >= total) return;
  int bf = (int)(idx / dd), r = (int)(idx % dd);
  int b = bf / F, f = bf - b*F;
  int mi = r/d, ni = r - mi*d;
  float2 acc = make_float2(0.f, 0.f);
  for (int c = 0; c < C; ++c) {
    float2 xv = xh[((long)b*C + c)*1024 + l*l + mi];
    float2 kv = kh[((long)c*F + f)*1024 + l*l + ni];
    acc.x += xv.x*kv.x - xv.y*kv.y;
    acc.y += xv.x*kv.y + xv.y*kv.x;
  }
  yl[(long)bf*Sout + offl_(l) + r] = acc;
}

// ---------------- per-degree complex GEMM, flat descending-l work list ------
__global__ __launch_bounds__(256)
void k_gemm(const float2* __restrict__ xh,
            const float* __restrict__ d0, const float2* __restrict__ wf,
            float2* __restrict__ yl, int ylS,
            int B, int C, int F, int L, int accf) {
  int rem = blockIdx.x;
  int l = L - 1, d = 0, tmc = 0, tnc = 0;
  for (; l >= 0; --l) {
    d = 2*l+1;
    tmc = (B*d + 63) >> 6; tnc = (F*d + 63) >> 6;
    int cnt = tmc*tnc;
    if (rem < cnt) break;
    rem -= cnt;
  }
  if (l < 0) return;
  const int ol = offl_(l);
  const int M = B*d, N = F*d, KD = C*d;
  const int tm = rem / tnc, tn = rem - tm*tnc;
  const int r0 = tm*64, q0 = tn*64;

  __shared__ float2 As[16][65];
  __shared__ float2 Bs[16][64];
  __shared__ unsigned char s_kc[1024], s_kp[1024], s_kmm[1024];
  __shared__ short s_qf[64];
  __shared__ unsigned char s_qni[64], s_qnn[64];

  const int tid = threadIdx.x;
  const int tx = tid & 15, ty = tid >> 4;

  for (int t = tid; t < KD; t += 256) {
    int c = t / d, p = t - c*d;
    s_kc[t] = (unsigned char)c;
    s_kp[t] = (unsigned char)p;
    s_kmm[t] = (unsigned char)((p - l + 192) % 6);
  }
  if (tid < 64) {
    int q = q0 + tid;
    if (q < N) {
      int f = q / d, ni = q - f*d;
      s_qf[tid] = (short)f;
      s_qni[tid] = (unsigned char)ni;
      s_qnn[tid] = (unsigned char)((ni - l + 192) % 6);
    } else s_qf[tid] = -1;
  }
  __syncthreads();

  const float2* Abase = xh + (size_t)B*C*ol;

  float2 acc[4][4];
  #pragma unroll
  for (int i = 0; i < 4; ++i)
    #pragma unroll
    for (int j = 0; j < 4; ++j) acc[i][j] = make_float2(0.f, 0.f);

  for (int kt = 0; kt < KD; kt += 16) {
    #pragma unroll
    for (int u = 0; u < 4; ++u) {
      int idx = tid + u*256;
      int kk = idx & 15, rr = idx >> 4;
      int r = r0 + rr, t = kt + kk;
      float2 v = make_float2(0.f, 0.f);
      if (r < M && t < KD) v = Abase[(size_t)r*KD + t];
      As[kk][rr] = v;
    }
    #pragma unroll
    for (int u = 0; u < 4; ++u) {
      int idx = tid + u*256;
      int qq = idx & 63, kk = idx >> 6;
      int t = kt + kk;
      float2 v = make_float2(0.f, 0.f);
      if (t < KD && s_qf[qq] >= 0) {
        int p = s_kp[t], c = s_kc[t];
        float dv = d0[ol + p*d + s_qni[qq]];
        float2 wv = wf[((size_t)c*F + s_qf[qq])*36 + s_kmm[t]*6 + s_qnn[qq]];
        v = make_float2(wv.x*dv, wv.y*dv);
      }
      Bs[kk][qq] = v;
    }
    __syncthreads();
    #pragma unroll
    for (int kk = 0; kk < 16; ++kk) {
      float2 a[4], b[4];
      #pragma unroll
      for (int i = 0; i < 4; ++i) a[i] = As[kk][ty + 16*i];
      #pragma unroll
      for (int j = 0; j < 4; ++j) b[j] = Bs[kk][tx + 16*j];
      #pragma unroll
      for (int i = 0; i < 4; ++i)
        #pragma unroll
        for (int j = 0; j < 4; ++j) {
          acc[i][j].x += a[i].x*b[j].x - a[i].y*b[j].y;
          acc[i][j].y += a[i].x*b[j].y + a[i].y*b[j].x;
        }
    }
    __syncthreads();
  }

  #pragma unroll
  for (int i = 0; i < 4; ++i) {
    int r = r0 + ty + 16*i;
    if (r >= M) continue;
    int b = r / d, mi = r - b*d;
    #pragma unroll
    for (int j = 0; j < 4; ++j) {
      int qq = tx + 16*j;
      if (s_qf[qq] < 0) continue;
      int f = s_qf[qq], ni = s_qni[qq];
      float2* o = yl + ((size_t)b*F + f)*ylS + ol + (size_t)mi*d + ni;
      if (accf) { float2 v = *o; v.x += acc[i][j].x; v.y += acc[i][j].y; *o = v; }
      else *o = acc[i][j];
    }
  }
}

// integrate over SO(3) at b=2 + linear head
__global__ void k_final(const float* __restrict__ h, const float* __restrict__ qw,
                        const float* __restrict__ lw, const float* __restrict__ lb,
                        float* __restrict__ out) {
  int b = blockIdx.x, f = threadIdx.x;
  const float* hp = h + ((long)b*256 + f)*64;
  float s = 0.f;
  for (int k = 0; k < 4; ++k) {
    float q = qw[k];
    for (int ag = 0; ag < 16; ++ag) s += hp[k*16 + ag]*q;
  }
  s = s * 0.0625f * lw[f];
  __shared__ float red[256];
  red[f] = s; __syncthreads();
  for (int st = 128; st > 0; st >>= 1) {
    if (f < st) red[f] += red[f + st];
    __syncthreads();
  }
  if (f == 0) out[b] = red[0] + lb[0];
}

// ============================================================================
extern "C" void kernel_launch(void* const* d_in, const int* in_sizes, int n_in,
                              void* d_out, int out_size, void* d_ws, size_t ws_size,
                              hipStream_t stream) {
  (void)in_sizes; (void)n_in;
  const float* x   = (const float*)d_in[0];
  const float* ks2 = (const float*)d_in[1];
  const float* lw  = (const float*)d_in[14];
  const float* lb  = (const float*)d_in[15];
  float* out = (float*)d_out;

  const int bl[5] = {32, 16, 8, 4, 2};
  char* ws = (char*)d_ws;
  size_t off = 0;
  auto alloc = [&](size_t nbytes) -> char* {
    char* p = ws + off;
    off += (nbytes + 255) & ~(size_t)255;
    return p;
  };

  double* lf = (double*)alloc(64*sizeof(double));
  float* qwT[5]; float* wigT[5]; float* d0T[4];
  for (int i = 0; i < 5; ++i) qwT[i]  = (float*)alloc((size_t)2*bl[i]*4);
  for (int i = 0; i < 5; ++i) wigT[i] = (float*)alloc((size_t)2*bl[i]*Sof(bl[i])*4);
  for (int i = 0; i < 4; ++i) d0T[i]  = (float*)alloc((size_t)Sof(bl[i])*4);

  float2* WF  = (float2*)alloc((size_t)128*256*36*8);
  float2* XH  = (float2*)alloc((size_t)64*43680*8);
  float2* YL  = (float2*)alloc((size_t)64*43680*8);
  float2* XHA = (float2*)alloc((size_t)64*5456*8);
  float2* XS2 = (float2*)alloc((size_t)1024*64*8);
  float2* XHS = (float2*)alloc((size_t)16*1024*8);
  float2* KHS = (float2*)alloc((size_t)64*1024*8);
  float*  OUTS= (float*)alloc((size_t)1024*64*4);
  size_t remain = (ws_size > off) ? (ws_size - off) : 0;
  size_t GCAP = remain > (64u<<20) ? (64u<<20) : (remain & ~(size_t)255);
  if (GCAP < (3u<<20)) {
    hipMemsetAsync(d_out, 0, (size_t)out_size*sizeof(float), stream);
    return;
  }
  float2* G = (float2*)alloc(GCAP);

  // ---- tables ----
  k_lf<<<1, 64, 0, stream>>>(lf);
  for (int i = 0; i < 5; ++i) k_qw<<<1, 64, 0, stream>>>(bl[i], qwT[i]);
  for (int i = 0; i < 5; ++i) {
    int L = bl[i], K = 2*L, md = 2*L-1;
    k_wigner<<<dim3(cdiv((long)K*md*md, 256), L), 256, 0, stream>>>(L, K, 0.0, lf, wigT[i]);
  }
  const double b0s[4] = {PI_D/16, PI_D/8, PI_D/4, PI_D/2};
  for (int i = 0; i < 4; ++i) {
    int L = bl[i], md = 2*L-1;
    k_wigner<<<dim3(cdiv((long)md*md, 256), L), 256, 0, stream>>>(L, 1, b0s[i], lf, d0T[i]);
  }

  // fused transition: yl -> [buildg+ifft2+relu+fft2] -> X chunks -> row-stream
  // analysis -> xh (GEMM-native)
  auto transition = [&](const float2* yl, int ylS, int Lsyn, const float* wsyn,
                        int K, const float* wana, const float* qana,
                        int Lana, float2* xh_out, int nsig, int Cout) {
    long perX = (long)K*K*K;
    int CH = (int)((long)(GCAP/8)/perX);
    if (CH > nsig) CH = nsig;
    if (CH < 1) CH = 1;
    size_t lds = sizeof(float2)*((size_t)K/2 + (size_t)K*(K+1) + (size_t)K*K/2);
    int nrows = 2*Lana - 1;
    for (int s0 = 0; s0 < nsig; s0 += CH) {
      int ch = (nsig - s0 < CH) ? (nsig - s0) : CH;
      k_trans<<<ch*K, 256, lds, stream>>>(yl + (size_t)s0*ylS, ylS, wsyn, Lsyn,
                                          G, nullptr, K, 1);
      k_ana2<<<ch*nrows, 256, 0, stream>>>(G, wana, qana, xh_out,
                                           K, Lana, s0, Cout, nsig);
    }
  };

  // conv: Wf table + flat descending-l GEMM
  auto conv = [&](const float* w, const float* d0, const float2* xh,
                  float2* yl, int ylS, int B, int C, int F, int L, int accf) {
    k_wf<<<cdiv((long)C*F*36, 256), 256, 0, stream>>>(w, WF, C*F);
    long tiles = 0;
    for (int l = 0; l < L; ++l) {
      int d = 2*l+1;
      tiles += (long)((B*d + 63)/64) * ((F*d + 63)/64);
    }
    k_gemm<<<dim3((unsigned)tiles), 256, 0, stream>>>(xh, d0, WF, yl, ylS, B, C, F, L, accf);
  };

  // ---- s2 conv (b=32) -> transition -> XH for block 1 ----
  k_dft1<<<1024, 64, 0, stream>>>(x, XS2, 64);
  k_analysis_s2<<<dim3(cdiv(16L*63, 256), 32), 256, 0, stream>>>(XS2, wigT[0], qwT[0], XHS, 16, 64);
  k_kh_s2<<<dim3(cdiv(64L*63, 256), 32), 256, 0, stream>>>(ks2, d0T[0], KHS, 4, 16);
  k_rank1<<<dim3(cdiv(64L*3969, 256), 32), 256, 0, stream>>>(XHS, KHS, YL, 4, 4, 16, 43680);
  transition(YL, 43680, 32, wigT[0], 64, wigT[0], qwT[0], 32, XH, 64, 16);

  // ---- residual blocks ----
  const float* wa_[4] = {(const float*)d_in[2], (const float*)d_in[5], (const float*)d_in[8],  (const float*)d_in[11]};
  const float* wb_[4] = {(const float*)d_in[3], (const float*)d_in[6], (const float*)d_in[9],  (const float*)d_in[12]};
  const float* wsn[4] = {(const float*)d_in[4], (const float*)d_in[7], (const float*)d_in[10], (const float*)d_in[13]};
  const int Cs[4] = {16, 32, 64, 128}, Fs[4] = {32, 64, 128, 256};

  for (int blk = 0; blk < 4; ++blk) {
    const int bw = bl[blk], C = Cs[blk], F = Fs[blk], B = 4;
    const int L = bw, Lh = bw/2, K = 2*bw, Kh = bw;
    const int Sa = Sof(L), Sh = Sof(Lh);

    conv(wa_[blk], d0T[blk], XH, YL, Sa, B, C, C, L, 0);
    transition(YL, Sa, L, wigT[blk], K, wigT[blk], qwT[blk], Lh, XHA, B*C, C);
    conv(wb_[blk], d0T[blk], XHA, YL, Sh, B, C, F, Lh, 0);
    conv(wsn[blk], d0T[blk], XH, YL, Sh, B, C, F, Lh, 1);

    if (blk < 3) {
      transition(YL, Sh, Lh, wigT[blk+1], Kh, wigT[blk+1], qwT[blk+1], Lh, XH, B*F, F);
    } else {
      size_t lds = sizeof(float2)*((size_t)Kh/2 + (size_t)Kh*(Kh+1) + (size_t)Kh*Kh/2);
      k_trans<<<B*F*Kh, 256, lds, stream>>>(YL, Sh, wigT[4], Lh, nullptr, OUTS, Kh, 0);
    }
  }

  // ---- integrate (b=2) + linear head ----
  k_final<<<4, 256, 0, stream>>>(OUTS, qwT[4], lw, lb, out);
}

// Round 9
// 6114.451 us; speedup vs baseline: 1.0693x; 1.0693x over previous
//
#include <hip/hip_runtime.h>
#include <math.h>

// ============================================================================
// S2CNN regression — round 8.
//  R7: k_ana2 fixed traffic but is sync-bound (2 barriers per k, 64 iters);
//  k_gemm b1a at 715us limited by critical-path l=31 blocks (63 k-iters) in
//  a 847-block grid (occ 18.5%).
//  This round:
//   * a-convs: split-K x2 WITHOUT atomics — halves write to YL / YL2; the
//     ha-transition's buildg sums yl+yl2 in its existing gather (free reduce).
//   * k_ana2: stage 8 k-rows per sync round (8x fewer barriers, 2KB coalesced
//     loads per round).
// ============================================================================

#define PI_D 3.14159265358979323846

__host__ __device__ __forceinline__ int offl_(int l) { return l*(2*l-1)*(2*l+1)/3; }
static inline int Sof(int b) { return b*(4*b*b-1)/3; }           // sum_{l<b}(2l+1)^2
static inline unsigned cdiv(long a, long b) { return (unsigned)((a + b - 1) / b); }

__device__ __constant__ float COS6[6] = {1.f, .5f, -.5f, -1.f, -.5f, .5f};
__device__ __constant__ float SIN6[6] = {0.f, 0.8660254037844386f, 0.8660254037844386f,
                                         0.f, -0.8660254037844386f, -0.8660254037844386f};

// ---------------- table generation ----------------
__global__ void k_lf(double* lf) {
  int n = threadIdx.x;
  double s = 0.0;
  for (int j = 2; j <= n; ++j) s += log((double)j);
  lf[n] = s;
}

__global__ void k_qw(int b, float* out) {
  int k = threadIdx.x, K = 2*b;
  if (k >= K) return;
  double beta = PI_D*(2*k+1)/(4.0*b);
  double s = 0.0;
  for (int j = 0; j < b; ++j)
    s += sin(PI_D*(double)(2*k+1)*(double)(2*j+1)/(4.0*b)) / (double)(2*j+1);
  out[k] = (float)((2.0/b)*sin(beta)*s);
}

// d^l_{m,n}(beta), explicit Jacobi sum, fp64.
__global__ void k_wigner(int L, int K, double beta0, const double* __restrict__ lf,
                         float* __restrict__ out) {
  int l = blockIdx.y;
  int d = 2*l+1, dd = d*d;
  long total = (long)K*dd;
  long idx = (long)blockIdx.x*blockDim.x + threadIdx.x;
  if (idx >= total) return;
  int k = (int)(idx / dd), r = (int)(idx % dd);
  int mi = r/d, ni = r - mi*d, m = mi-l, n = ni-l;
  double beta = (K == 1) ? beta0 : PI_D*(double)(2*k+1)/(2.0*K);
  double cb = cos(0.5*beta), sb = sin(0.5*beta);
  double lc = log(cb), ls = log(sb);
  double pref = 0.5*(lf[l+m]+lf[l-m]+lf[l+n]+lf[l-n]);
  int smin = (n-m > 0) ? (n-m) : 0;
  int smax = (l+n < l-m) ? (l+n) : (l-m);
  double sum = 0.0;
  for (int s = smin; s <= smax; ++s) {
    double t = pref - lf[l+n-s] - lf[s] - lf[m-n+s] - lf[l-m-s]
             + (double)(2*l+n-m-2*s)*lc + (double)(m-n+2*s)*ls;
    double e = exp(t);
    sum += ((m-n+s) & 1) ? -e : e;
  }
  out[(long)K*offl_(l) + idx] = (float)sum;
}

// ---------------- s2 front: 1-D forward DFT (centered output) ----------------
__global__ void k_dft1(const float* __restrict__ in, float2* __restrict__ out, int K) {
  __shared__ float row[64];
  int tid = threadIdx.x;
  long base = (long)blockIdx.x * K;
  row[tid] = in[base + tid];
  __syncthreads();
  int i = tid;
  float2 acc = make_float2(0.f, 0.f);
  float c0 = 6.28318530717958647692f / K;
  for (int j = 0; j < K; ++j) {
    int r = (j * ((K + K/2 - i) & (K-1))) & (K-1);
    float s, c; sincosf(c0 * (float)r, &s, &c);
    acc.x += row[j]*c; acc.y += row[j]*s;
  }
  out[base + i] = acc;
}

// ---------------- fused transition kernel ----------------
__device__ __forceinline__ void fft_axis(float2* T, int P, float2* S, const float2* TW,
                                         int K, int axis, float fsign,
                                         int tid, int bs) {
  const int half = K >> 1;
  int stages = 0; for (int t = K; t > 1; t >>= 1) ++stages;
  for (int b0 = 0; b0 < K; b0 += half) {
    int cur = 0;
    int l = half, m = 1;
    for (int s = 0; s < stages; ++s) {
      for (int t = tid; t < half*half; t += bs) {
        int line = t / half, b = t - (t/half)*half;
        int j = b / m, k = b - (b/m)*m;
        int i0 = k + j*m, i1 = i0 + l*m;
        int o0 = k + 2*j*m, o1 = o0 + m;
        float2 a, bb;
        if (cur == 0) {
          int t0i = axis ? (i0*P + b0 + line) : ((b0+line)*P + i0);
          int t1i = axis ? (i1*P + b0 + line) : ((b0+line)*P + i1);
          a = T[t0i]; bb = T[t1i];
        } else {
          a = S[line*K + i0]; bb = S[line*K + i1];
        }
        float2 w = TW[j*m]; w.y *= fsign;
        float2 dv = make_float2(a.x - bb.x, a.y - bb.y);
        float2 t1 = make_float2(dv.x*w.x - dv.y*w.y, dv.x*w.y + dv.y*w.x);
        float2 t0 = make_float2(a.x + bb.x, a.y + bb.y);
        if (cur == 0) {
          S[line*K + o0] = t0; S[line*K + o1] = t1;
        } else {
          int d0i = axis ? (o0*P + b0 + line) : ((b0+line)*P + o0);
          int d1i = axis ? (o1*P + b0 + line) : ((b0+line)*P + o1);
          T[d0i] = t0; T[d1i] = t1;
        }
      }
      __syncthreads();
      cur ^= 1; l >>= 1; m <<= 1;
    }
    if (cur == 1) {
      for (int t = tid; t < half*K; t += bs) {
        int line = t / K, e = t - (t/K)*K;
        int ti = axis ? (e*P + b0 + line) : ((b0+line)*P + e);
        T[ti] = S[line*K + e];
      }
      __syncthreads();
    }
  }
}

__global__ void k_trans(const float2* __restrict__ yl, const float2* __restrict__ yl2,
                        int ylS, const float* __restrict__ wig, int Lsyn,
                        float2* __restrict__ outX, float* __restrict__ outR,
                        int K, int fwd) {
  extern __shared__ float2 smc[];
  const int P = K + 1;
  float2* TW = smc;
  float2* T  = smc + K/2;
  float2* S  = T + K*P;
  const int tid = threadIdx.x, bs = blockDim.x;
  const int ci = blockIdx.x / K, k = blockIdx.x - ci*K;
  const int KK = K*K, Kh = K/2;
  const float c0 = 6.28318530717958647692f / K;
  for (int t = tid; t < Kh; t += bs) {
    float s, c; sincosf(c0 * (float)t, &s, &c);
    TW[t] = make_float2(c, -s);
  }
  for (int idx = tid; idx < KK; idx += bs) {
    int fm = idx / K, fn = idx - (idx/K)*K;
    int m = (fm ^ Kh) - Kh, n = (fn ^ Kh) - Kh;
    int am = m < 0 ? -m : m, an = n < 0 ? -n : n;
    int lmin = am > an ? am : an;
    float2 acc = make_float2(0.f, 0.f);
    for (int l = lmin; l < Lsyn; ++l) {
      int d = 2*l+1;
      int r = (m+l)*d + (n+l);
      size_t yi = (size_t)ci*ylS + offl_(l) + r;
      float wv = wig[(size_t)K*offl_(l) + (size_t)k*d*d + r];
      float2 yv = yl[yi];
      if (yl2) { float2 y2 = yl2[yi]; yv.x += y2.x; yv.y += y2.y; }
      acc.x += wv*yv.x; acc.y += wv*yv.y;
    }
    T[fm*P + fn] = acc;
  }
  __syncthreads();
  fft_axis(T, P, S, TW, K, 0, -1.f, tid, bs);
  fft_axis(T, P, S, TW, K, 1, -1.f, tid, bs);
  for (int idx = tid; idx < KK; idx += bs) {
    int fm = idx / K, fn = idx - (idx/K)*K;
    T[fm*P + fn] = make_float2(fmaxf(T[fm*P + fn].x, 0.f), 0.f);
  }
  __syncthreads();
  if (fwd) {
    fft_axis(T, P, S, TW, K, 0, 1.f, tid, bs);
    fft_axis(T, P, S, TW, K, 1, 1.f, tid, bs);
    float2* o = outX + ((size_t)ci*K + k)*KK;
    for (int idx = tid; idx < KK; idx += bs)
      o[idx] = T[(idx/K)*P + (idx - (idx/K)*K)];
  } else {
    float* o = outR + ((size_t)ci*K + k)*KK;
    for (int idx = tid; idx < KK; idx += bs)
      o[idx] = T[(idx/K)*P + (idx - (idx/K)*K)].x;
  }
}

// ---------------- row-streaming Wigner analysis (8-row staged) ----------------
// One block per (chunk-signal, freq-row m); 8 k-rows staged per sync round.
// Writes xh in GEMM-native layout: xh[BCall*offl(l) + (b*d+mi)*C*d + c*d + ni]
__global__ __launch_bounds__(256)
void k_ana2(const float2* __restrict__ X, const float* __restrict__ wig,
            const float* __restrict__ qw, float2* __restrict__ xh,
            int K, int Lana, int s0, int C, int BCall) {
  const int nrows = 2*Lana - 1;
  const int bcl = blockIdx.x / nrows;
  const int rowi = blockIdx.x - bcl*nrows;
  const int m = rowi - (Lana - 1);
  const int am = m < 0 ? -m : m;
  const int fm = (m + K) & (K - 1);
  const int bc = s0 + bcl;
  const int b = bc / C, c = bc - b*C;
  const int nout = Lana*Lana - am*am;
  const int tid = threadIdx.x;

  __shared__ float2 rows[8][64];
  __shared__ float qs[64];

  float2 acc[4] = {{0,0},{0,0},{0,0},{0,0}};
  int obase[4], odd[4], ofn[4];
  size_t oaddr[4];
  int ocnt = 0;
  for (int oi = tid; oi < nout && ocnt < 4; oi += 256) {
    int rem = oi, l = am;
    while (rem >= 2*l+1) { rem -= 2*l+1; ++l; }
    int ni = rem, d = 2*l+1;
    int mi = m + l;
    obase[ocnt] = K*offl_(l) + mi*d + ni;
    odd[ocnt]   = d*d;
    int n = ni - l;
    ofn[ocnt]   = (n + K) & (K-1);
    oaddr[ocnt] = (size_t)BCall*offl_(l) + ((size_t)(b*d + mi)*C + c)*d + ni;
    ++ocnt;
  }

  for (int t = tid; t < K; t += 256) qs[t] = qw[t];

  const float2* Xrow = X + (size_t)bcl*K*K*K + (size_t)fm*K;
  for (int k0 = 0; k0 < K; k0 += 8) {
    __syncthreads();
    for (int t = tid; t < 8*K; t += 256) {
      int kk = t / K, e = t - kk*K;
      rows[kk][e] = Xrow[(size_t)(k0+kk)*K*K + e];
    }
    __syncthreads();
    #pragma unroll
    for (int kk = 0; kk < 8; ++kk) {
      float q = qs[k0+kk];
      #pragma unroll 4
      for (int u = 0; u < ocnt; ++u) {
        float wv = wig[obase[u] + (k0+kk)*odd[u]] * q;
        float2 xv = rows[kk][ofn[u]];
        acc[u].x += wv*xv.x;
        acc[u].y += wv*xv.y;
      }
    }
  }
  for (int u = 0; u < ocnt; ++u) xh[oaddr[u]] = acc[u];
}

// s2 variant: XS2 CENTERED (from k_dft1). stride 1024, offset l^2.
__global__ void k_analysis_s2(const float2* __restrict__ X, const float* __restrict__ wig,
                              const float* __restrict__ qw, float2* __restrict__ xh,
                              int BC, int K) {
  int l = blockIdx.y, d = 2*l+1, dd = d*d;
  long total = (long)BC*d;
  long idx = (long)blockIdx.x*blockDim.x + threadIdx.x;
  if (idx >= total) return;
  int bc = (int)(idx / d), mi = (int)(idx % d), m = mi - l;
  const float* wl = wig + (long)K*offl_(l);
  float2 acc = make_float2(0.f, 0.f);
  for (int k = 0; k < K; ++k) {
    float w = qw[k] * wl[(long)k*dd + mi*d + l];
    float2 xv = X[((long)bc*K + k)*K + (K/2+m)];
    acc.x += w*xv.x; acc.y += w*xv.y;
  }
  xh[(long)bc*1024 + l*l + mi] = acc;
}

// ---------------- 6x6 phase table of the SO(3) conv weights ----------------
__global__ void k_wf(const float* __restrict__ w, float2* __restrict__ wf, int CF) {
  long idx = (long)blockIdx.x*blockDim.x + threadIdx.x;
  if (idx >= (long)CF*36) return;
  int cf = (int)(idx / 36), r = (int)(idx % 36);
  int mm = r / 6, nn = r - (r/6)*6;
  const float* wp = w + (long)cf*36;
  float re = 0.f, im = 0.f;
  for (int a = 0; a < 6; ++a) {
    int pa = (mm*a) % 6;
    for (int g = 0; g < 6; ++g) {
      int p = (pa + nn*g) % 6;
      float wv = wp[a*6 + g];
      re += wv*COS6[p]; im += wv*SIN6[p];
    }
  }
  wf[idx] = make_float2(re, im);
}

__global__ void k_kh_s2(const float* __restrict__ w, const float* __restrict__ d0,
                        float2* __restrict__ kh, int C, int F) {
  int l = blockIdx.y, d = 2*l+1;
  long total = (long)C*F*d;
  long idx = (long)blockIdx.x*blockDim.x + threadIdx.x;
  if (idx >= total) return;
  int cf = (int)(idx / d), mi = (int)(idx % d), m = mi - l;
  const float* wp = w + (long)cf*6;
  float re = 0.f, im = 0.f;
  for (int j = 0; j < 6; ++j) {
    int p = ((-m*j) % 6 + 6) % 6;
    re += wp[j]*COS6[p]; im += wp[j]*SIN6[p];
  }
  float dv = d0[offl_(l) + mi*d + l];
  kh[(long)cf*1024 + l*l + mi] = make_float2(re*dv, im*dv);
}

// s2 rank-1: yl[b,f,m,n] = sum_c xh[b,c,m]*kh[c,f,n]
__global__ void k_rank1(const float2* __restrict__ xh, const float2* __restrict__ kh,
                        float2* __restrict__ yl, int B, int C, int F, int Sout) {
  int l = blockIdx.y, d = 2*l+1, dd = d*d;
  long total = (long)B*F*dd;
  long idx = (long)blockIdx.x*blockDim.x + threadIdx.x;
  if (idx >= total) return;
  int bf = (int)(idx / dd), r = (int)(idx % dd);
  int b = bf / F, f = bf - b*F;
  int mi = r/d, ni = r - mi*d;
  float2 acc = make_float2(0.f, 0.f);
  for (int c = 0; c < C; ++c) {
    float2 xv = xh[((long)b*C + c)*1024 + l*l + mi];
    float2 kv = kh[((long)c*F + f)*1024 + l*l + ni];
    acc.x += xv.x*kv.x - xv.y*kv.y;
    acc.y += xv.x*kv.y + xv.y*kv.x;
  }
  yl[(long)bf*Sout + offl_(l) + r] = acc;
}

// ---------------- per-degree complex GEMM ----------------
// Flat descending-l work list; optional split-K x2 via blockIdx.y:
//   split 0 -> yl, split 1 -> yl2 (no atomics; consumer sums).
__global__ __launch_bounds__(256)
void k_gemm(const float2* __restrict__ xh,
            const float* __restrict__ d0, const float2* __restrict__ wf,
            float2* __restrict__ yl, float2* __restrict__ yl2, int ylS,
            int B, int C, int F, int L, int accf) {
  int rem = blockIdx.x;
  int l = L - 1, d = 0, tmc = 0, tnc = 0;
  for (; l >= 0; --l) {
    d = 2*l+1;
    tmc = (B*d + 63) >> 6; tnc = (F*d + 63) >> 6;
    int cnt = tmc*tnc;
    if (rem < cnt) break;
    rem -= cnt;
  }
  if (l < 0) return;
  const int ol = offl_(l);
  const int M = B*d, N = F*d, KD = C*d;
  const int tm = rem / tnc, tn = rem - tm*tnc;
  const int r0 = tm*64, q0 = tn*64;

  int khalf = KD;
  if (gridDim.y > 1) khalf = (((KD + 1) >> 1) + 15) & ~15;
  int kt0 = blockIdx.y * khalf;
  int kt1 = kt0 + khalf; if (kt1 > KD) kt1 = KD;
  float2* outp = (blockIdx.y == 0) ? yl : yl2;

  __shared__ float2 As[16][65];
  __shared__ float2 Bs[16][64];
  __shared__ unsigned char s_kc[1024], s_kp[1024], s_kmm[1024];
  __shared__ short s_qf[64];
  __shared__ unsigned char s_qni[64], s_qnn[64];

  const int tid = threadIdx.x;
  const int tx = tid & 15, ty = tid >> 4;

  for (int t = tid; t < KD; t += 256) {
    int c = t / d, p = t - c*d;
    s_kc[t] = (unsigned char)c;
    s_kp[t] = (unsigned char)p;
    s_kmm[t] = (unsigned char)((p - l + 192) % 6);
  }
  if (tid < 64) {
    int q = q0 + tid;
    if (q < N) {
      int f = q / d, ni = q - f*d;
      s_qf[tid] = (short)f;
      s_qni[tid] = (unsigned char)ni;
      s_qnn[tid] = (unsigned char)((ni - l + 192) % 6);
    } else s_qf[tid] = -1;
  }
  __syncthreads();

  const float2* Abase = xh + (size_t)B*C*ol;

  float2 acc[4][4];
  #pragma unroll
  for (int i = 0; i < 4; ++i)
    #pragma unroll
    for (int j = 0; j < 4; ++j) acc[i][j] = make_float2(0.f, 0.f);

  for (int kt = kt0; kt < kt1; kt += 16) {
    #pragma unroll
    for (int u = 0; u < 4; ++u) {
      int idx = tid + u*256;
      int kk = idx & 15, rr = idx >> 4;
      int r = r0 + rr, t = kt + kk;
      float2 v = make_float2(0.f, 0.f);
      if (r < M && t < kt1) v = Abase[(size_t)r*KD + t];
      As[kk][rr] = v;
    }
    #pragma unroll
    for (int u = 0; u < 4; ++u) {
      int idx = tid + u*256;
      int qq = idx & 63, kk = idx >> 6;
      int t = kt + kk;
      float2 v = make_float2(0.f, 0.f);
      if (t < kt1 && s_qf[qq] >= 0) {
        int p = s_kp[t], c = s_kc[t];
        float dv = d0[ol + p*d + s_qni[qq]];
        float2 wv = wf[((size_t)c*F + s_qf[qq])*36 + s_kmm[t]*6 + s_qnn[qq]];
        v = make_float2(wv.x*dv, wv.y*dv);
      }
      Bs[kk][qq] = v;
    }
    __syncthreads();
    #pragma unroll
    for (int kk = 0; kk < 16; ++kk) {
      float2 a[4], b[4];
      #pragma unroll
      for (int i = 0; i < 4; ++i) a[i] = As[kk][ty + 16*i];
      #pragma unroll
      for (int j = 0; j < 4; ++j) b[j] = Bs[kk][tx + 16*j];
      #pragma unroll
      for (int i = 0; i < 4; ++i)
        #pragma unroll
        for (int j = 0; j < 4; ++j) {
          acc[i][j].x += a[i].x*b[j].x - a[i].y*b[j].y;
          acc[i][j].y += a[i].x*b[j].y + a[i].y*b[j].x;
        }
    }
    __syncthreads();
  }

  #pragma unroll
  for (int i = 0; i < 4; ++i) {
    int r = r0 + ty + 16*i;
    if (r >= M) continue;
    int b = r / d, mi = r - b*d;
    #pragma unroll
    for (int j = 0; j < 4; ++j) {
      int qq = tx + 16*j;
      if (s_qf[qq] < 0) continue;
      int f = s_qf[qq], ni = s_qni[qq];
      float2* o = outp + ((size_t)b*F + f)*ylS + ol + (size_t)mi*d + ni;
      if (accf) { float2 v = *o; v.x += acc[i][j].x; v.y += acc[i][j].y; *o = v; }
      else *o = acc[i][j];
    }
  }
}

// integrate over SO(3) at b=2 + linear head
__global__ void k_final(const float* __restrict__ h, const float* __restrict__ qw,
                        const float* __restrict__ lw, const float* __restrict__ lb,
                        float* __restrict__ out) {
  int b = blockIdx.x, f = threadIdx.x;
  const float* hp = h + ((long)b*256 + f)*64;
  float s = 0.f;
  for (int k = 0; k < 4; ++k) {
    float q = qw[k];
    for (int ag = 0; ag < 16; ++ag) s += hp[k*16 + ag]*q;
  }
  s = s * 0.0625f * lw[f];
  __shared__ float red[256];
  red[f] = s; __syncthreads();
  for (int st = 128; st > 0; st >>= 1) {
    if (f < st) red[f] += red[f + st];
    __syncthreads();
  }
  if (f == 0) out[b] = red[0] + lb[0];
}

// ============================================================================
extern "C" void kernel_launch(void* const* d_in, const int* in_sizes, int n_in,
                              void* d_out, int out_size, void* d_ws, size_t ws_size,
                              hipStream_t stream) {
  (void)in_sizes; (void)n_in;
  const float* x   = (const float*)d_in[0];
  const float* ks2 = (const float*)d_in[1];
  const float* lw  = (const float*)d_in[14];
  const float* lb  = (const float*)d_in[15];
  float* out = (float*)d_out;

  const int bl[5] = {32, 16, 8, 4, 2};
  char* ws = (char*)d_ws;
  size_t off = 0;
  auto alloc = [&](size_t nbytes) -> char* {
    char* p = ws + off;
    off += (nbytes + 255) & ~(size_t)255;
    return p;
  };

  double* lf = (double*)alloc(64*sizeof(double));
  float* qwT[5]; float* wigT[5]; float* d0T[4];
  for (int i = 0; i < 5; ++i) qwT[i]  = (float*)alloc((size_t)2*bl[i]*4);
  for (int i = 0; i < 5; ++i) wigT[i] = (float*)alloc((size_t)2*bl[i]*Sof(bl[i])*4);
  for (int i = 0; i < 4; ++i) d0T[i]  = (float*)alloc((size_t)Sof(bl[i])*4);

  float2* WF  = (float2*)alloc((size_t)128*256*36*8);
  float2* XH  = (float2*)alloc((size_t)64*43680*8);
  float2* YL  = (float2*)alloc((size_t)64*43680*8);
  float2* YL2 = (float2*)alloc((size_t)64*43680*8);
  float2* XHA = (float2*)alloc((size_t)64*5456*8);
  float2* XS2 = (float2*)alloc((size_t)1024*64*8);
  float2* XHS = (float2*)alloc((size_t)16*1024*8);
  float2* KHS = (float2*)alloc((size_t)64*1024*8);
  float*  OUTS= (float*)alloc((size_t)1024*64*4);
  size_t remain = (ws_size > off) ? (ws_size - off) : 0;
  size_t GCAP = remain > (64u<<20) ? (64u<<20) : (remain & ~(size_t)255);
  if (GCAP < (3u<<20)) {
    hipMemsetAsync(d_out, 0, (size_t)out_size*sizeof(float), stream);
    return;
  }
  float2* G = (float2*)alloc(GCAP);

  // ---- tables ----
  k_lf<<<1, 64, 0, stream>>>(lf);
  for (int i = 0; i < 5; ++i) k_qw<<<1, 64, 0, stream>>>(bl[i], qwT[i]);
  for (int i = 0; i < 5; ++i) {
    int L = bl[i], K = 2*L, md = 2*L-1;
    k_wigner<<<dim3(cdiv((long)K*md*md, 256), L), 256, 0, stream>>>(L, K, 0.0, lf, wigT[i]);
  }
  const double b0s[4] = {PI_D/16, PI_D/8, PI_D/4, PI_D/2};
  for (int i = 0; i < 4; ++i) {
    int L = bl[i], md = 2*L-1;
    k_wigner<<<dim3(cdiv((long)md*md, 256), L), 256, 0, stream>>>(L, 1, b0s[i], lf, d0T[i]);
  }

  // fused transition: yl(+yl2) -> [buildg+ifft2+relu+fft2] -> X -> k_ana2 -> xh
  auto transition = [&](const float2* yl, const float2* yl2, int ylS, int Lsyn,
                        const float* wsyn, int K, const float* wana, const float* qana,
                        int Lana, float2* xh_out, int nsig, int Cout) {
    long perX = (long)K*K*K;
    int CH = (int)((long)(GCAP/8)/perX);
    if (CH > nsig) CH = nsig;
    if (CH < 1) CH = 1;
    size_t lds = sizeof(float2)*((size_t)K/2 + (size_t)K*(K+1) + (size_t)K*K/2);
    int nrows = 2*Lana - 1;
    for (int s0 = 0; s0 < nsig; s0 += CH) {
      int ch = (nsig - s0 < CH) ? (nsig - s0) : CH;
      k_trans<<<ch*K, 256, lds, stream>>>(yl + (size_t)s0*ylS,
                                          yl2 ? yl2 + (size_t)s0*ylS : nullptr,
                                          ylS, wsyn, Lsyn, G, nullptr, K, 1);
      k_ana2<<<ch*nrows, 256, 0, stream>>>(G, wana, qana, xh_out,
                                           K, Lana, s0, Cout, nsig);
    }
  };

  // conv: Wf table + flat descending-l GEMM (optional split-K x2)
  auto conv = [&](const float* w, const float* d0, const float2* xh,
                  float2* yl, float2* yl2, int ylS, int B, int C, int F, int L,
                  int accf, int nsplit) {
    k_wf<<<cdiv((long)C*F*36, 256), 256, 0, stream>>>(w, WF, C*F);
    long tiles = 0;
    for (int l = 0; l < L; ++l) {
      int d = 2*l+1;
      tiles += (long)((B*d + 63)/64) * ((F*d + 63)/64);
    }
    k_gemm<<<dim3((unsigned)tiles, nsplit), 256, 0, stream>>>(
        xh, d0, WF, yl, yl2, ylS, B, C, F, L, accf);
  };

  // ---- s2 conv (b=32) -> transition -> XH for block 1 ----
  k_dft1<<<1024, 64, 0, stream>>>(x, XS2, 64);
  k_analysis_s2<<<dim3(cdiv(16L*63, 256), 32), 256, 0, stream>>>(XS2, wigT[0], qwT[0], XHS, 16, 64);
  k_kh_s2<<<dim3(cdiv(64L*63, 256), 32), 256, 0, stream>>>(ks2, d0T[0], KHS, 4, 16);
  k_rank1<<<dim3(cdiv(64L*3969, 256), 32), 256, 0, stream>>>(XHS, KHS, YL, 4, 4, 16, 43680);
  transition(YL, nullptr, 43680, 32, wigT[0], 64, wigT[0], qwT[0], 32, XH, 64, 16);

  // ---- residual blocks ----
  const float* wa_[4] = {(const float*)d_in[2], (const float*)d_in[5], (const float*)d_in[8],  (const float*)d_in[11]};
  const float* wb_[4] = {(const float*)d_in[3], (const float*)d_in[6], (const float*)d_in[9],  (const float*)d_in[12]};
  const float* wsn[4] = {(const float*)d_in[4], (const float*)d_in[7], (const float*)d_in[10], (const float*)d_in[13]};
  const int Cs[4] = {16, 32, 64, 128}, Fs[4] = {32, 64, 128, 256};

  for (int blk = 0; blk < 4; ++blk) {
    const int bw = bl[blk], C = Cs[blk], F = Fs[blk], B = 4;
    const int L = bw, Lh = bw/2, K = 2*bw, Kh = bw;
    const int Sa = Sof(L), Sh = Sof(Lh);

    // a-conv: split-K x2 -> YL + YL2 (summed in ha-transition)
    conv(wa_[blk], d0T[blk], XH, YL, YL2, Sa, B, C, C, L, 0, 2);
    transition(YL, YL2, Sa, L, wigT[blk], K, wigT[blk], qwT[blk], Lh, XHA, B*C, C);
    // b-conv + shortcut (sequential accumulate, single buffer)
    conv(wb_[blk], d0T[blk], XHA, YL, nullptr, Sh, B, C, F, Lh, 0, 1);
    conv(wsn[blk], d0T[blk], XH, YL, nullptr, Sh, B, C, F, Lh, 1, 1);

    if (blk < 3) {
      transition(YL, nullptr, Sh, Lh, wigT[blk+1], Kh, wigT[blk+1], qwT[blk+1], Lh, XH, B*F, F);
    } else {
      size_t lds = sizeof(float2)*((size_t)Kh/2 + (size_t)Kh*(Kh+1) + (size_t)Kh*Kh/2);
      k_trans<<<B*F*Kh, 256, lds, stream>>>(YL, nullptr, Sh, wigT[4], Lh, nullptr, OUTS, Kh, 0);
    }
  }

  // ---- integrate (b=2) + linear head ----
  k_final<<<4, 256, 0, stream>>>(OUTS, qwT[4], lw, lb, out);
}